// Round 10
// baseline (282.727 us; speedup 1.0000x reference)
//
#include <hip/hip_runtime.h>
#include <cmath>

typedef __attribute__((ext_vector_type(8))) __bf16 bf16x8;
typedef __attribute__((ext_vector_type(4))) float f32x4;
typedef _Float16 f16;
typedef __attribute__((ext_vector_type(2))) _Float16 f16x2;

__device__ inline unsigned short f2bf(float x) {
  union { float f; unsigned u; } v; v.f = x;
  unsigned r = v.u + 0x7fff + ((v.u >> 16) & 1);   // RNE
  return (unsigned short)(r >> 16);
}

__device__ inline void cvt8_store(unsigned short* dst, float4 a, float4 b) {
  ushort4 lo, hi;
  lo.x = f2bf(a.x); lo.y = f2bf(a.y); lo.z = f2bf(a.z); lo.w = f2bf(a.w);
  hi.x = f2bf(b.x); hi.y = f2bf(b.y); hi.z = f2bf(b.z); hi.w = f2bf(b.w);
  *(ushort4*)dst = lo; *(ushort4*)(dst + 4) = hi;
}

// ---------------------------------------------------------------------------
// LDS union across phases: max 33,280 B -> 4 blocks/CU (133 KB of 160 KB)
// ---------------------------------------------------------------------------
struct SMemG0 { unsigned short As[64][72]; unsigned short Bs[64][72]; f16 nl[64][72]; };
struct SMemAt { f16 qs[64][64]; f16 ks[64][64]; f16 vs[64][64]; f16 ss[64][68]; };
union SMem { SMemG0 g0; SMemAt at; };

// ---------------------------------------------------------------------------
// 2-level grid barrier: 64 leaves (16 blocks each) -> 1 root. Device scope.
// Slot layout (uints): leaf i at [i*32], root at [2048]. Slot stride 4096.
// ---------------------------------------------------------------------------
__device__ inline void gsync(unsigned* bar) {
  __syncthreads();
  if (threadIdx.x == 0) {
    __threadfence();                       // publish this block's writes
    unsigned* leaf = bar + (blockIdx.x & 63) * 32;
    unsigned* root = bar + 2048;
    unsigned p = __hip_atomic_fetch_add(leaf, 1u, __ATOMIC_ACQ_REL,
                                        __HIP_MEMORY_SCOPE_AGENT);
    if (p == 15u)                          // last of this leaf's 16 blocks
      __hip_atomic_fetch_add(root, 1u, __ATOMIC_ACQ_REL,
                             __HIP_MEMORY_SCOPE_AGENT);
    while (__hip_atomic_load(root, __ATOMIC_RELAXED,
                             __HIP_MEMORY_SCOPE_AGENT) < 64u)
      __builtin_amdgcn_s_sleep(1);
    (void)__hip_atomic_load(root, __ATOMIC_ACQUIRE, __HIP_MEMORY_SCOPE_AGENT);
  }
  __syncthreads();
}

__global__ __launch_bounds__(256) void k_init(unsigned* __restrict__ bar) {
  uint4 z; z.x = 0; z.y = 0; z.z = 0; z.w = 0;
  *(uint4*)&bar[(blockIdx.x * 256 + threadIdx.x) * 4] = z;
}

// ---------------------------------------------------------------------------
// Mega-kernel: entire pipeline, 1024 blocks x 256 threads, 4 grid barriers.
// ---------------------------------------------------------------------------
__global__ __launch_bounds__(256, 4) void k_mega(
    const float* __restrict__ hin, const float* __restrict__ Wq,
    const float* __restrict__ Wkv, const float* __restrict__ lam,
    const float* __restrict__ Wqt, const float* __restrict__ Wkt,
    const float* __restrict__ Wvt, const float* __restrict__ Wo,
    const float* __restrict__ gamma, const float* __restrict__ beta,
    f16* __restrict__ qkvh, f16* __restrict__ ctxp,
    unsigned short* __restrict__ avb, float* __restrict__ ao,
    unsigned* __restrict__ bar, float* __restrict__ outp)
{
  __shared__ SMem sm;
  const int blk = blockIdx.x;
  const int tid = threadIdx.x;

  // ============ P1: QKV GEMM + norm + tropical linear (blocks 0..383) ======
  if (blk < 384) {
    const int bx = blk % 24, by = blk / 24;
    const int r0 = by * 64, c0 = bx * 64;
    const int which = c0 >> 9;            // 0=q,1=k,2=v
    const int hh = bx & 7;                // head
    const float* Wt = (which == 0) ? Wqt : (which == 1) ? Wkt : Wvt;
    const int w = tid >> 6, l = tid & 63;
    const int wr = (w >> 1) * 32, wc = (w & 1) * 32;
    const int srow = tid >> 3, sk8 = (tid & 7) * 8;
    // per-lane tropical weight row, packed fp16 (32 VGPRs)
    f16x2 wreg[32];
    #pragma unroll
    for (int i = 0; i < 64; i += 4) {
      f32x4 wv = *(const f32x4*)&Wt[l * 64 + i];
      wreg[i / 2]     = f16x2{ (f16)wv[0], (f16)wv[1] };
      wreg[i / 2 + 1] = f16x2{ (f16)wv[2], (f16)wv[3] };
    }
    f32x4 acc[2][2] = {};
    for (int kk = 0; kk < 512; kk += 64) {
      __syncthreads();
      #pragma unroll
      for (int q2 = 0; q2 < 2; ++q2) {
        int row = srow + q2 * 32;
        const float* ap = &hin[(r0 + row) * 512 + kk + sk8];
        cvt8_store(&sm.g0.As[row][sk8], *(const float4*)ap, *(const float4*)(ap + 4));
        int c = c0 + row;
        const float* wrp = (c < 512) ? (Wq + c * 512) : (Wkv + (c - 512) * 512);
        cvt8_store(&sm.g0.Bs[row][sk8], *(const float4*)&wrp[kk + sk8],
                   *(const float4*)&wrp[kk + sk8 + 4]);
      }
      __syncthreads();
      #pragma unroll
      for (int ks = 0; ks < 2; ++ks) {
        const int kc = ks * 32 + (l >> 4) * 8;
        bf16x8 a0 = *(const bf16x8*)&sm.g0.As[wr +      (l & 15)][kc];
        bf16x8 a1 = *(const bf16x8*)&sm.g0.As[wr + 16 + (l & 15)][kc];
        bf16x8 b0 = *(const bf16x8*)&sm.g0.Bs[wc +      (l & 15)][kc];
        bf16x8 b1 = *(const bf16x8*)&sm.g0.Bs[wc + 16 + (l & 15)][kc];
        acc[0][0] = __builtin_amdgcn_mfma_f32_16x16x32_bf16(a0, b0, acc[0][0], 0, 0, 0);
        acc[0][1] = __builtin_amdgcn_mfma_f32_16x16x32_bf16(a0, b1, acc[0][1], 0, 0, 0);
        acc[1][0] = __builtin_amdgcn_mfma_f32_16x16x32_bf16(a1, b0, acc[1][0], 0, 0, 0);
        acc[1][1] = __builtin_amdgcn_mfma_f32_16x16x32_bf16(a1, b1, acc[1][1], 0, 0, 0);
      }
    }
    #pragma unroll
    for (int i = 0; i < 2; ++i)
      #pragma unroll
      for (int j = 0; j < 2; ++j)
        #pragma unroll
        for (int r = 0; r < 4; ++r) {
          int rl = wr + i * 16 + (l >> 4) * 4 + r;
          int cl = wc + j * 16 + (l & 15);
          sm.g0.nl[rl][cl] = (f16)(log1pf(fmaxf(acc[i][j][r], 0.f)) - lam[hh * 64 + cl]);
        }
    __syncthreads();
    const f16 NEGI = (f16)(-INFINITY);
    #pragma unroll 2
    for (int it = 0; it < 16; ++it) {
      int lr = w + it * 4;               // wave-uniform row -> broadcast reads
      f16x2 m2 = f16x2{ NEGI, NEGI };
      #pragma unroll
      for (int i = 0; i < 8; ++i) {
        f16x2 nv[4];
        *(int4*)&nv[0] = *(const int4*)&sm.g0.nl[lr][i * 8];
        m2 = __builtin_elementwise_max(m2, nv[0] + wreg[i * 4 + 0]);
        m2 = __builtin_elementwise_max(m2, nv[1] + wreg[i * 4 + 1]);
        m2 = __builtin_elementwise_max(m2, nv[2] + wreg[i * 4 + 2]);
        m2 = __builtin_elementwise_max(m2, nv[3] + wreg[i * 4 + 3]);
      }
      f16 m = (m2[0] > m2[1]) ? m2[0] : m2[1];
      int r = r0 + lr;
      int s = r >> 1, bb = r & 1;
      int g = bb * 8 + (s >> 6);
      int p = ((s & 63) << 3) | hh;
      qkvh[which * 524288 + ((g << 9) + p) * 64 + l] = m;
    }
  }
  gsync(bar);            // qkvh ready

  // ============ P2: tropical attention (all 1024 blocks) ===================
  {
    const int pt = blk >> 7;            // 0..7
    const int g  = (blk >> 3) & 15;     // 0..15
    const int cs = blk & 7;             // 0..7
    const f16* qb = qkvh +           (size_t)g * 512 * 64;
    const f16* kb = qkvh + 524288  + (size_t)g * 512 * 64;
    const f16* vb = qkvh + 1048576 + (size_t)g * 512 * 64;
    const int tr = tid >> 4, tc = tid & 15;
    {
      int row = tid >> 3, blk8 = tid & 7;
      int c0 = cs * 64;
      #pragma unroll
      for (int q2 = 0; q2 < 2; ++q2) {
        int r = row + q2 * 32;
        int sb = (blk8 ^ (r & 7)) * 8;
        *(int4*)&sm.at.qs[r][sb] = *(const int4*)&qb[(pt * 64 + r) * 64 + blk8 * 8];
        *(int4*)&sm.at.ks[r][sb] = *(const int4*)&kb[(c0 + r) * 64 + blk8 * 8];
        *(int4*)&sm.at.vs[r][sb] = *(const int4*)&vb[(c0 + r) * 64 + blk8 * 8];
      }
    }
    __syncthreads();
    const f16 NEGI = (f16)(-INFINITY);
    const f16 POSI = (f16)(INFINITY);
    const f16x2 NEG2 = { NEGI, NEGI };
    const f16x2 POS2 = { POSI, POSI };
    f16x2 mx2[4][4], mn2[4][4];
    #pragma unroll
    for (int i = 0; i < 4; ++i)
      #pragma unroll
      for (int m = 0; m < 4; ++m) { mx2[i][m] = NEG2; mn2[i][m] = POS2; }
    #pragma unroll
    for (int b = 0; b < 8; ++b) {
      f16x2 qv[4][4], kv[4][4];
      #pragma unroll
      for (int i = 0; i < 4; ++i) {
        int r = 4 * tr + i;
        *(int4*)&qv[i][0] = *(const int4*)&sm.at.qs[r][(b ^ (r & 7)) * 8];
      }
      #pragma unroll
      for (int m = 0; m < 4; ++m)
        *(int4*)&kv[m][0] = *(const int4*)&sm.at.ks[tc + 16 * m][(b ^ (tc & 7)) * 8];
      #pragma unroll
      for (int i = 0; i < 4; ++i)
        #pragma unroll
        for (int m = 0; m < 4; ++m)
          #pragma unroll
          for (int e = 0; e < 4; ++e) {
            f16x2 d = qv[i][e] - kv[m][e];
            mx2[i][m] = __builtin_elementwise_max(mx2[i][m], d);
            mn2[i][m] = __builtin_elementwise_min(mn2[i][m], d);
          }
    }
    #pragma unroll
    for (int i = 0; i < 4; ++i)
      #pragma unroll
      for (int m = 0; m < 4; ++m) {
        f16 mxv = (mx2[i][m][0] > mx2[i][m][1]) ? mx2[i][m][0] : mx2[i][m][1];
        f16 mnv = (mn2[i][m][0] < mn2[i][m][1]) ? mn2[i][m][0] : mn2[i][m][1];
        sm.at.ss[tc + 16 * m][4 * tr + i] = mnv - mxv;
      }
    __syncthreads();
    f16x2 ctx[4][4];
    #pragma unroll
    for (int i = 0; i < 4; ++i)
      #pragma unroll
      for (int j = 0; j < 4; ++j) ctx[i][j] = NEG2;
    const int ch = tc >> 3, dg = tc & 7;
    #pragma unroll
    for (int gi = 0; gi < 4; ++gi) {
      #pragma unroll
      for (int e = 0; e < 8; ++e) {
        int c = ch * 32 + gi * 8 + e;
        f16x2 vv[4];
        *(int4*)&vv[0] = *(const int4*)&sm.at.vs[c][(dg ^ (c & 7)) * 8];
        f16 sr[4];
        *(int2*)&sr[0] = *(const int2*)&sm.at.ss[c][4 * tr];
        #pragma unroll
        for (int i = 0; i < 4; ++i) {
          f16x2 s2 = { sr[i], sr[i] };
          #pragma unroll
          for (int j = 0; j < 4; ++j)
            ctx[i][j] = __builtin_elementwise_max(ctx[i][j], s2 + vv[j]);
        }
      }
    }
    #pragma unroll
    for (int i = 0; i < 4; ++i)
      #pragma unroll
      for (int j = 0; j < 4; ++j) {
        int o = __shfl_xor(*(int*)&ctx[i][j], 8);
        ctx[i][j] = __builtin_elementwise_max(ctx[i][j], *(f16x2*)&o);
      }
    if (tc < 8) {
      size_t base = (size_t)cs * 524288 + (size_t)g * 32768
                  + (size_t)(pt * 64 + 4 * tr) * 64 + dg * 8;
      #pragma unroll
      for (int i = 0; i < 4; ++i) {
        int4 o;
        ((f16x2*)&o)[0] = ctx[i][0];
        ((f16x2*)&o)[1] = ctx[i][1];
        ((f16x2*)&o)[2] = ctx[i][2];
        ((f16x2*)&o)[3] = ctx[i][3];
        *(int4*)&ctxp[base + i * 64] = o;
      }
    }
  }
  gsync(bar + 4096);     // ctxp ready

  // ============ P3: combine 8 c-splits -> avb (blocks 0..255) ==============
  if (blk < 256) {
    int idx = blk * 256 + tid;
    int dblk = idx & 7, p = (idx >> 3) & 511, g = idx >> 12;
    const f16* cp = ctxp + (size_t)g * 32768 + p * 64 + dblk * 8;
    f16x2 m[4];
    *(int4*)&m[0] = *(const int4*)cp;
    #pragma unroll
    for (int cs = 1; cs < 8; ++cs) {
      f16x2 t[4];
      *(int4*)&t[0] = *(const int4*)(cp + (size_t)cs * 524288);
      #pragma unroll
      for (int e = 0; e < 4; ++e) m[e] = __builtin_elementwise_max(m[e], t[e]);
    }
    ushort4 lo, hi;
    lo.x = f2bf(expm1f((float)m[0][0]));
    lo.y = f2bf(expm1f((float)m[0][1]));
    lo.z = f2bf(expm1f((float)m[1][0]));
    lo.w = f2bf(expm1f((float)m[1][1]));
    hi.x = f2bf(expm1f((float)m[2][0]));
    hi.y = f2bf(expm1f((float)m[2][1]));
    hi.z = f2bf(expm1f((float)m[3][0]));
    hi.w = f2bf(expm1f((float)m[3][1]));
    unsigned short* dst = avb + (p * 2 + (g >> 3)) * 512 + (g & 7) * 64 + dblk * 8;
    *(ushort4*)dst = lo;
    *(ushort4*)(dst + 4) = hi;
  }
  gsync(bar + 8192);     // avb ready

  // ============ P4: output GEMM (blocks 0..127) ============================
  if (blk < 128) {
    const int r0 = (blk >> 3) * 64, c0 = (blk & 7) * 64;
    const int w = tid >> 6, l = tid & 63;
    const int wr = (w >> 1) * 32, wc = (w & 1) * 32;
    const int srow = tid >> 3, sk8 = (tid & 7) * 8;
    f32x4 acc[2][2] = {};
    for (int kk = 0; kk < 512; kk += 64) {
      __syncthreads();
      #pragma unroll
      for (int q2 = 0; q2 < 2; ++q2) {
        int row = srow + q2 * 32;
        *(int4*)&sm.g0.As[row][sk8] = *(const int4*)&avb[(r0 + row) * 512 + kk + sk8];
        const float* bp = &Wo[(c0 + row) * 512 + kk + sk8];
        cvt8_store(&sm.g0.Bs[row][sk8], *(const float4*)bp, *(const float4*)(bp + 4));
      }
      __syncthreads();
      #pragma unroll
      for (int ks = 0; ks < 2; ++ks) {
        const int kc = ks * 32 + (l >> 4) * 8;
        bf16x8 a0 = *(const bf16x8*)&sm.g0.As[wr +      (l & 15)][kc];
        bf16x8 a1 = *(const bf16x8*)&sm.g0.As[wr + 16 + (l & 15)][kc];
        bf16x8 b0 = *(const bf16x8*)&sm.g0.Bs[wc +      (l & 15)][kc];
        bf16x8 b1 = *(const bf16x8*)&sm.g0.Bs[wc + 16 + (l & 15)][kc];
        acc[0][0] = __builtin_amdgcn_mfma_f32_16x16x32_bf16(a0, b0, acc[0][0], 0, 0, 0);
        acc[0][1] = __builtin_amdgcn_mfma_f32_16x16x32_bf16(a0, b1, acc[0][1], 0, 0, 0);
        acc[1][0] = __builtin_amdgcn_mfma_f32_16x16x32_bf16(a1, b0, acc[1][0], 0, 0, 0);
        acc[1][1] = __builtin_amdgcn_mfma_f32_16x16x32_bf16(a1, b1, acc[1][1], 0, 0, 0);
      }
    }
    #pragma unroll
    for (int i = 0; i < 2; ++i)
      #pragma unroll
      for (int j = 0; j < 2; ++j)
        #pragma unroll
        for (int r = 0; r < 4; ++r) {
          int row = r0 + wr + i * 16 + (l >> 4) * 4 + r;
          int col = c0 + wc + j * 16 + (l & 15);
          ao[row * 512 + col] = acc[i][j][r];
        }
  }
  gsync(bar + 12288);    // ao ready

  // ============ P5: residual + LayerNorm (blocks 0..255) ===================
  if (blk < 256) {
    const int r = blk * 4 + (tid >> 6);
    const int lane = tid & 63;
    const int c0 = lane * 8;
    f32x4 h0 = *(const f32x4*)&hin[r * 512 + c0];
    f32x4 h1 = *(const f32x4*)&hin[r * 512 + c0 + 4];
    f32x4 a0 = *(const f32x4*)&ao[r * 512 + c0];
    f32x4 a1 = *(const f32x4*)&ao[r * 512 + c0 + 4];
    float x[8];
    #pragma unroll
    for (int e = 0; e < 4; ++e) { x[e] = h0[e] + a0[e]; x[4 + e] = h1[e] + a1[e]; }
    float sum = 0.f, sq = 0.f;
    #pragma unroll
    for (int e = 0; e < 8; ++e) { sum += x[e]; sq += x[e] * x[e]; }
    #pragma unroll
    for (int o = 32; o > 0; o >>= 1) {
      sum += __shfl_xor(sum, o);
      sq  += __shfl_xor(sq, o);
    }
    float mu  = sum * (1.f / 512.f);
    float var = sq * (1.f / 512.f) - mu * mu;
    float rstd = rsqrtf(fmaxf(var, 0.f) + 1e-5f);
    f32x4 o0, o1;
    #pragma unroll
    for (int e = 0; e < 4; ++e) {
      o0[e] = (x[e]     - mu) * rstd * gamma[c0 + e]     + beta[c0 + e];
      o1[e] = (x[4 + e] - mu) * rstd * gamma[c0 + 4 + e] + beta[c0 + 4 + e];
    }
    *(f32x4*)&outp[r * 512 + c0]     = o0;
    *(f32x4*)&outp[r * 512 + c0 + 4] = o1;
  }
}

// ---------------------------------------------------------------------------
extern "C" void kernel_launch(void* const* d_in, const int* in_sizes, int n_in,
                              void* d_out, int out_size, void* d_ws, size_t ws_size,
                              hipStream_t stream) {
  const float* hin   = (const float*)d_in[0];
  const float* Wq    = (const float*)d_in[1];
  const float* Wkv   = (const float*)d_in[2];
  const float* Wqt   = (const float*)d_in[3];
  const float* Wkt   = (const float*)d_in[4];
  const float* Wvt   = (const float*)d_in[5];
  const float* lam   = (const float*)d_in[6];
  const float* Wo    = (const float*)d_in[7];
  const float* gamma = (const float*)d_in[8];
  const float* beta  = (const float*)d_in[9];
  char* wsb = (char*)d_ws;
  // byte layout: [0,3M) qkvh fp16 | [4M,12M) ctxp fp16 | [13M,14M) avb bf16
  //              [14M,16M) ao fp32 | [16M,16M+64K) barrier slots
  f16*            qkvh = (f16*)wsb;
  f16*            ctxp = (f16*)(wsb + (4u << 20));
  unsigned short* avb  = (unsigned short*)(wsb + (13u << 20));
  float*          ao   = (float*)(wsb + (14u << 20));
  unsigned*       bar  = (unsigned*)(wsb + (16u << 20));
  float*          out  = (float*)d_out;

  k_init<<<16, 256, 0, stream>>>(bar);
  k_mega<<<1024, 256, 0, stream>>>(hin, Wq, Wkv, lam, Wqt, Wkt, Wvt, Wo,
                                   gamma, beta, qkvh, ctxp, avb, ao, bar, out);
}

// Round 11
// 181.010 us; speedup vs baseline: 1.5619x; 1.5619x over previous
//
#include <hip/hip_runtime.h>
#include <cmath>

typedef __attribute__((ext_vector_type(8))) __bf16 bf16x8;
typedef __attribute__((ext_vector_type(4))) float f32x4;
typedef _Float16 f16;
typedef __attribute__((ext_vector_type(2))) _Float16 f16x2;

namespace {
constexpr int GP = 512;
}

__device__ inline unsigned short f2bf(float x) {
  union { float f; unsigned u; } v; v.f = x;
  unsigned r = v.u + 0x7fff + ((v.u >> 16) & 1);   // RNE
  return (unsigned short)(r >> 16);
}

__device__ inline void cvt8_store(unsigned short* dst, float4 a, float4 b) {
  ushort4 lo, hi;
  lo.x = f2bf(a.x); lo.y = f2bf(a.y); lo.z = f2bf(a.z); lo.w = f2bf(a.w);
  hi.x = f2bf(b.x); hi.y = f2bf(b.y); hi.z = f2bf(b.z); hi.w = f2bf(b.w);
  *(ushort4*)dst = lo; *(ushort4*)(dst + 4) = hi;
}

// ---------------------------------------------------------------------------
// Kernel 1: QKV projection (bf16 MFMA) + log1p(relu)-lam + fp16 tropical
// linear + scramble-write of q/k/v (fp16).  grid (24,16).
// Block (0,0) also zeroes the 160 ticket counters used by later kernels.
// ---------------------------------------------------------------------------
__global__ __launch_bounds__(256) void k_gemm0t(const float* __restrict__ h,
    const float* __restrict__ Wq, const float* __restrict__ Wkv,
    const float* __restrict__ lam, const float* __restrict__ Wqt,
    const float* __restrict__ Wkt, const float* __restrict__ Wvt,
    f16* __restrict__ qkvh, unsigned* __restrict__ tick)
{
  __shared__ unsigned short As[64][72];
  __shared__ unsigned short Bs[64][72];
  __shared__ float Wl[64][65];
  __shared__ f16 nl[64][72];
  const int tid = threadIdx.x;
  if (blockIdx.x == 0 && blockIdx.y == 0 && tid < 160) tick[tid] = 0u;
  const int bx = blockIdx.x;
  const int r0 = blockIdx.y * 64, c0 = bx * 64;
  const int which = c0 >> 9;            // 0=q,1=k,2=v
  const int hh = bx & 7;                // head
  const float* Wt = (which == 0) ? Wqt : (which == 1) ? Wkt : Wvt;
  #pragma unroll
  for (int q = 0; q < 16; ++q) {
    int idx = q * 256 + tid;
    Wl[idx >> 6][idx & 63] = Wt[idx];
  }
  const int w = tid >> 6, l = tid & 63;
  const int wr = (w >> 1) * 32, wc = (w & 1) * 32;
  const int srow = tid >> 3, sk8 = (tid & 7) * 8;
  f32x4 acc[2][2] = {};
  for (int kk = 0; kk < 512; kk += 64) {
    __syncthreads();
    #pragma unroll
    for (int q2 = 0; q2 < 2; ++q2) {
      int row = srow + q2 * 32;
      const float* ap = &h[(r0 + row) * 512 + kk + sk8];
      cvt8_store(&As[row][sk8], *(const float4*)ap, *(const float4*)(ap + 4));
      int c = c0 + row;
      const float* wrp = (c < 512) ? (Wq + c * 512) : (Wkv + (c - 512) * 512);
      cvt8_store(&Bs[row][sk8], *(const float4*)&wrp[kk + sk8],
                 *(const float4*)&wrp[kk + sk8 + 4]);
    }
    __syncthreads();
    #pragma unroll
    for (int ks = 0; ks < 2; ++ks) {
      const int kc = ks * 32 + (l >> 4) * 8;
      bf16x8 a0 = *(const bf16x8*)&As[wr +      (l & 15)][kc];
      bf16x8 a1 = *(const bf16x8*)&As[wr + 16 + (l & 15)][kc];
      bf16x8 b0 = *(const bf16x8*)&Bs[wc +      (l & 15)][kc];
      bf16x8 b1 = *(const bf16x8*)&Bs[wc + 16 + (l & 15)][kc];
      acc[0][0] = __builtin_amdgcn_mfma_f32_16x16x32_bf16(a0, b0, acc[0][0], 0, 0, 0);
      acc[0][1] = __builtin_amdgcn_mfma_f32_16x16x32_bf16(a0, b1, acc[0][1], 0, 0, 0);
      acc[1][0] = __builtin_amdgcn_mfma_f32_16x16x32_bf16(a1, b0, acc[1][0], 0, 0, 0);
      acc[1][1] = __builtin_amdgcn_mfma_f32_16x16x32_bf16(a1, b1, acc[1][1], 0, 0, 0);
    }
  }
  #pragma unroll
  for (int i = 0; i < 2; ++i)
    #pragma unroll
    for (int j = 0; j < 2; ++j)
      #pragma unroll
      for (int r = 0; r < 4; ++r) {
        int rl = wr + i * 16 + (l >> 4) * 4 + r;
        int cl = wc + j * 16 + (l & 15);
        nl[rl][cl] = (f16)(log1pf(fmaxf(acc[i][j][r], 0.f)) - lam[hh * 64 + cl]);
      }
  __syncthreads();
  // per-lane tropical weight row, packed fp16 (32 VGPRs)
  f16x2 wreg[32];
  #pragma unroll
  for (int i = 0; i < 64; i += 2)
    wreg[i / 2] = f16x2{ (f16)Wl[l][i], (f16)Wl[l][i + 1] };
  const f16 NEGI = (f16)(-INFINITY);
  #pragma unroll 2
  for (int it = 0; it < 16; ++it) {
    int lr = w + it * 4;                 // wave-uniform row -> broadcast reads
    f16x2 m2 = f16x2{ NEGI, NEGI };
    #pragma unroll
    for (int i = 0; i < 8; ++i) {
      f16x2 nv[4];
      *(int4*)&nv[0] = *(const int4*)&nl[lr][i * 8];
      m2 = __builtin_elementwise_max(m2, nv[0] + wreg[i * 4 + 0]);
      m2 = __builtin_elementwise_max(m2, nv[1] + wreg[i * 4 + 1]);
      m2 = __builtin_elementwise_max(m2, nv[2] + wreg[i * 4 + 2]);
      m2 = __builtin_elementwise_max(m2, nv[3] + wreg[i * 4 + 3]);
    }
    f16 m = (m2[0] > m2[1]) ? m2[0] : m2[1];
    int r = r0 + lr;
    int s = r >> 1, bb = r & 1;
    int g = bb * 8 + (s >> 6);
    int p = ((s & 63) << 3) | hh;
    qkvh[which * 524288 + ((g << 9) + p) * 64 + l] = m;
  }
}

// ---------------------------------------------------------------------------
// Kernel 2: tropical attention (packed fp16, 64p x 64c per block,
// grid (8 pt, 16 g, 8 cs)) + LAST-ARRIVER combine: the 8th cs-block of each
// (g,pt) tile maxes the 8 partials, applies expm1, writes bf16 avb.
// No spin-waits anywhere.
// ---------------------------------------------------------------------------
__global__ __launch_bounds__(256) void k_attn(const f16* __restrict__ qkv,
    f16* __restrict__ ctxp, unsigned short* __restrict__ avb,
    unsigned* __restrict__ tick)
{
  const int pt = blockIdx.x;        // 0..7
  const int g  = blockIdx.y;        // 0..15
  const int cs = blockIdx.z;        // 0..7
  const f16* qb = qkv +           (size_t)g * GP * 64;
  const f16* kb = qkv + 524288  + (size_t)g * GP * 64;
  const f16* vb = qkv + 1048576 + (size_t)g * GP * 64;
  __shared__ f16 qs[64][64];
  __shared__ f16 ks[64][64];
  __shared__ f16 vs[64][64];
  __shared__ f16 ss[64][68];        // transposed: [c][p]
  __shared__ unsigned lastf;
  const int tid = threadIdx.x;
  const int tr = tid >> 4, tc = tid & 15;
  {
    int row = tid >> 3, blk8 = tid & 7;
    int c0 = cs * 64;
    #pragma unroll
    for (int q2 = 0; q2 < 2; ++q2) {
      int r = row + q2 * 32;
      int sb = (blk8 ^ (r & 7)) * 8;
      *(int4*)&qs[r][sb] = *(const int4*)&qb[(pt * 64 + r) * 64 + blk8 * 8];
      *(int4*)&ks[r][sb] = *(const int4*)&kb[(c0 + r) * 64 + blk8 * 8];
      *(int4*)&vs[r][sb] = *(const int4*)&vb[(c0 + r) * 64 + blk8 * 8];
    }
  }
  __syncthreads();
  const f16 NEGI = (f16)(-INFINITY);
  const f16 POSI = (f16)(INFINITY);
  const f16x2 NEG2 = { NEGI, NEGI };
  const f16x2 POS2 = { POSI, POSI };
  // ---- phase 1: 16 scores (rows 4tr+i, cols tc+16m), d packed 2/op ----
  f16x2 mx2[4][4], mn2[4][4];
  #pragma unroll
  for (int i = 0; i < 4; ++i)
    #pragma unroll
    for (int m = 0; m < 4; ++m) { mx2[i][m] = NEG2; mn2[i][m] = POS2; }
  #pragma unroll
  for (int b = 0; b < 8; ++b) {
    f16x2 qv[4][4], kv[4][4];
    #pragma unroll
    for (int i = 0; i < 4; ++i) {
      int r = 4 * tr + i;
      *(int4*)&qv[i][0] = *(const int4*)&qs[r][(b ^ (r & 7)) * 8];
    }
    #pragma unroll
    for (int m = 0; m < 4; ++m)
      *(int4*)&kv[m][0] = *(const int4*)&ks[tc + 16 * m][(b ^ (tc & 7)) * 8];
    #pragma unroll
    for (int i = 0; i < 4; ++i)
      #pragma unroll
      for (int m = 0; m < 4; ++m)
        #pragma unroll
        for (int e = 0; e < 4; ++e) {
          f16x2 d = qv[i][e] - kv[m][e];
          mx2[i][m] = __builtin_elementwise_max(mx2[i][m], d);
          mn2[i][m] = __builtin_elementwise_min(mn2[i][m], d);
        }
  }
  #pragma unroll
  for (int i = 0; i < 4; ++i)
    #pragma unroll
    for (int m = 0; m < 4; ++m) {
      f16 mxv = (mx2[i][m][0] > mx2[i][m][1]) ? mx2[i][m][0] : mx2[i][m][1];
      f16 mnv = (mn2[i][m][0] < mn2[i][m][1]) ? mn2[i][m][0] : mn2[i][m][1];
      ss[tc + 16 * m][4 * tr + i] = mnv - mxv;
    }
  __syncthreads();
  // ---- phase 2: ctx over c-half (tc>>3), dims group dg = tc&7 ----
  f16x2 ctx[4][4];
  #pragma unroll
  for (int i = 0; i < 4; ++i)
    #pragma unroll
    for (int j = 0; j < 4; ++j) ctx[i][j] = NEG2;
  const int ch = tc >> 3, dg = tc & 7;
  #pragma unroll
  for (int gi = 0; gi < 4; ++gi) {
    #pragma unroll
    for (int e = 0; e < 8; ++e) {
      int c = ch * 32 + gi * 8 + e;
      f16x2 vv[4];
      *(int4*)&vv[0] = *(const int4*)&vs[c][(dg ^ (c & 7)) * 8];
      f16 sr[4];
      *(int2*)&sr[0] = *(const int2*)&ss[c][4 * tr];
      #pragma unroll
      for (int i = 0; i < 4; ++i) {
        f16x2 s2 = { sr[i], sr[i] };
        #pragma unroll
        for (int j = 0; j < 4; ++j)
          ctx[i][j] = __builtin_elementwise_max(ctx[i][j], s2 + vv[j]);
      }
    }
  }
  #pragma unroll
  for (int i = 0; i < 4; ++i)
    #pragma unroll
    for (int j = 0; j < 4; ++j) {
      int o = __shfl_xor(*(int*)&ctx[i][j], 8);
      ctx[i][j] = __builtin_elementwise_max(ctx[i][j], *(f16x2*)&o);
    }
  if (tc < 8) {
    size_t base = (size_t)cs * 524288 + (size_t)g * 32768
                + (size_t)(pt * 64 + 4 * tr) * 64 + dg * 8;
    #pragma unroll
    for (int i = 0; i < 4; ++i) {
      int4 o;
      ((f16x2*)&o)[0] = ctx[i][0];
      ((f16x2*)&o)[1] = ctx[i][1];
      ((f16x2*)&o)[2] = ctx[i][2];
      ((f16x2*)&o)[3] = ctx[i][3];
      *(int4*)&ctxp[base + i * 64] = o;
    }
  }
  // ---- last-arriver combine for this (g,pt) tile ----
  __syncthreads();
  __threadfence();                      // publish ctxp writes (agent scope)
  if (tid == 0) {
    unsigned t = __hip_atomic_fetch_add(&tick[g * 8 + pt], 1u,
                                        __ATOMIC_ACQ_REL,
                                        __HIP_MEMORY_SCOPE_AGENT);
    lastf = (t == 7u) ? 1u : 0u;
  }
  __syncthreads();
  if (lastf) {
    __threadfence();                    // acquire: invalidate stale caches
    #pragma unroll
    for (int q2 = 0; q2 < 2; ++q2) {
      int idx = q2 * 256 + tid;         // 0..511 int4s of this tile
      int dblk = idx & 7, row = idx >> 3;
      int p = pt * 64 + row;
      const f16* cp = ctxp + (size_t)g * 32768 + (size_t)p * 64 + dblk * 8;
      f16x2 m[4];
      *(int4*)&m[0] = *(const int4*)cp;
      #pragma unroll
      for (int cs2 = 1; cs2 < 8; ++cs2) {
        f16x2 t4[4];
        *(int4*)&t4[0] = *(const int4*)(cp + (size_t)cs2 * 524288);
        #pragma unroll
        for (int e = 0; e < 4; ++e) m[e] = __builtin_elementwise_max(m[e], t4[e]);
      }
      ushort4 lo, hi;
      lo.x = f2bf(expm1f((float)m[0][0]));
      lo.y = f2bf(expm1f((float)m[0][1]));
      lo.z = f2bf(expm1f((float)m[1][0]));
      lo.w = f2bf(expm1f((float)m[1][1]));
      hi.x = f2bf(expm1f((float)m[2][0]));
      hi.y = f2bf(expm1f((float)m[2][1]));
      hi.z = f2bf(expm1f((float)m[3][0]));
      hi.w = f2bf(expm1f((float)m[3][1]));
      unsigned short* dst = avb + (p * 2 + (g >> 3)) * 512 + (g & 7) * 64 + dblk * 8;
      *(ushort4*)dst = lo;
      *(ushort4*)(dst + 4) = hi;
    }
  }
}

// ---------------------------------------------------------------------------
// Kernel 3: output GEMM (A = bf16 avb, B = Wo cvt in staging) + LAST-ARRIVER
// LayerNorm: the 8th column-block of each 64-row block LayerNorms those rows.
// ---------------------------------------------------------------------------
__global__ __launch_bounds__(256) void k_gemm1c(const unsigned short* __restrict__ avb,
    const float* __restrict__ Wo, float* __restrict__ ao,
    const float* __restrict__ hin, const float* __restrict__ gamma,
    const float* __restrict__ beta, float* __restrict__ outp,
    unsigned* __restrict__ tick)
{
  __shared__ unsigned short As[64][72];
  __shared__ unsigned short Bs[64][72];
  __shared__ unsigned lastf;
  const int tid = threadIdx.x;
  const int r0 = blockIdx.y * 64, c0 = blockIdx.x * 64;
  const int w = tid >> 6, l = tid & 63;
  const int wr = (w >> 1) * 32, wc = (w & 1) * 32;
  const int srow = tid >> 3, sk8 = (tid & 7) * 8;
  f32x4 acc[2][2] = {};
  for (int kk = 0; kk < 512; kk += 64) {
    __syncthreads();
    #pragma unroll
    for (int q2 = 0; q2 < 2; ++q2) {
      int row = srow + q2 * 32;
      *(int4*)&As[row][sk8] = *(const int4*)&avb[(r0 + row) * 512 + kk + sk8];
      const float* bp = &Wo[(c0 + row) * 512 + kk + sk8];
      cvt8_store(&Bs[row][sk8], *(const float4*)bp, *(const float4*)(bp + 4));
    }
    __syncthreads();
    #pragma unroll
    for (int ks = 0; ks < 2; ++ks) {
      const int kc = ks * 32 + (l >> 4) * 8;
      bf16x8 a0 = *(const bf16x8*)&As[wr +      (l & 15)][kc];
      bf16x8 a1 = *(const bf16x8*)&As[wr + 16 + (l & 15)][kc];
      bf16x8 b0 = *(const bf16x8*)&Bs[wc +      (l & 15)][kc];
      bf16x8 b1 = *(const bf16x8*)&Bs[wc + 16 + (l & 15)][kc];
      acc[0][0] = __builtin_amdgcn_mfma_f32_16x16x32_bf16(a0, b0, acc[0][0], 0, 0, 0);
      acc[0][1] = __builtin_amdgcn_mfma_f32_16x16x32_bf16(a0, b1, acc[0][1], 0, 0, 0);
      acc[1][0] = __builtin_amdgcn_mfma_f32_16x16x32_bf16(a1, b0, acc[1][0], 0, 0, 0);
      acc[1][1] = __builtin_amdgcn_mfma_f32_16x16x32_bf16(a1, b1, acc[1][1], 0, 0, 0);
    }
  }
  #pragma unroll
  for (int i = 0; i < 2; ++i)
    #pragma unroll
    for (int j = 0; j < 2; ++j)
      #pragma unroll
      for (int r = 0; r < 4; ++r) {
        int row = r0 + wr + i * 16 + (l >> 4) * 4 + r;
        int col = c0 + wc + j * 16 + (l & 15);
        ao[row * 512 + col] = acc[i][j][r];
      }
  // ---- last-arriver LayerNorm for rows r0..r0+63 ----
  __syncthreads();
  __threadfence();                      // publish ao writes
  if (tid == 0) {
    unsigned t = __hip_atomic_fetch_add(&tick[128 + blockIdx.y], 1u,
                                        __ATOMIC_ACQ_REL,
                                        __HIP_MEMORY_SCOPE_AGENT);
    lastf = (t == 7u) ? 1u : 0u;
  }
  __syncthreads();
  if (lastf) {
    __threadfence();                    // acquire
    const int lane = tid & 63;
    const int cc = lane * 8;
    #pragma unroll 2
    for (int it = 0; it < 16; ++it) {
      int r = r0 + it * 4 + w;
      f32x4 h0 = *(const f32x4*)&hin[r * 512 + cc];
      f32x4 h1 = *(const f32x4*)&hin[r * 512 + cc + 4];
      f32x4 a0 = *(const f32x4*)&ao[r * 512 + cc];
      f32x4 a1 = *(const f32x4*)&ao[r * 512 + cc + 4];
      float x[8];
      #pragma unroll
      for (int e = 0; e < 4; ++e) { x[e] = h0[e] + a0[e]; x[4 + e] = h1[e] + a1[e]; }
      float sum = 0.f, sq = 0.f;
      #pragma unroll
      for (int e = 0; e < 8; ++e) { sum += x[e]; sq += x[e] * x[e]; }
      #pragma unroll
      for (int o = 32; o > 0; o >>= 1) {
        sum += __shfl_xor(sum, o);
        sq  += __shfl_xor(sq, o);
      }
      float mu  = sum * (1.f / 512.f);
      float var = sq * (1.f / 512.f) - mu * mu;
      float rstd = rsqrtf(fmaxf(var, 0.f) + 1e-5f);
      f32x4 o0, o1;
      #pragma unroll
      for (int e = 0; e < 4; ++e) {
        o0[e] = (x[e]     - mu) * rstd * gamma[cc + e]     + beta[cc + e];
        o1[e] = (x[4 + e] - mu) * rstd * gamma[cc + 4 + e] + beta[cc + 4 + e];
      }
      *(f32x4*)&outp[r * 512 + cc]     = o0;
      *(f32x4*)&outp[r * 512 + cc + 4] = o1;
    }
  }
}

// ---------------------------------------------------------------------------
extern "C" void kernel_launch(void* const* d_in, const int* in_sizes, int n_in,
                              void* d_out, int out_size, void* d_ws, size_t ws_size,
                              hipStream_t stream) {
  const float* hin   = (const float*)d_in[0];
  const float* Wq    = (const float*)d_in[1];
  const float* Wkv   = (const float*)d_in[2];
  const float* Wqt   = (const float*)d_in[3];
  const float* Wkt   = (const float*)d_in[4];
  const float* Wvt   = (const float*)d_in[5];
  const float* lam   = (const float*)d_in[6];
  const float* Wo    = (const float*)d_in[7];
  const float* gamma = (const float*)d_in[8];
  const float* beta  = (const float*)d_in[9];
  char* wsb = (char*)d_ws;
  // byte layout: [0,3M)  qkvh fp16 (dead after attn; ao fp32 overlays [0,2M))
  //              [4M,5M) avb bf16 | [6M,14M) ctxp fp16 (8 x 1MB)
  //              [15M,15M+640B) tickets (zeroed by gemm0t block (0,0))
  f16*            qkvh = (f16*)wsb;
  f16*            ctxp = (f16*)(wsb + 6291456);
  unsigned short* avb  = (unsigned short*)(wsb + 4194304);
  float*          ao   = (float*)wsb;
  unsigned*       tick = (unsigned*)(wsb + 15728640);
  float*          out  = (float*)d_out;

  k_gemm0t<<<dim3(24, 16),   256, 0, stream>>>(hin, Wq, Wkv, lam, Wqt, Wkt, Wvt,
                                               qkvh, tick);
  k_attn  <<<dim3(8, 16, 8), 256, 0, stream>>>(qkvh, ctxp, avb, tick);
  k_gemm1c<<<dim3(8, 16),    256, 0, stream>>>(avb, Wo, ao, hin, gamma, beta,
                                               out, tick);
}

// Round 12
// 71.819 us; speedup vs baseline: 3.9367x; 2.5204x over previous
//
#include <hip/hip_runtime.h>
#include <cmath>

typedef __attribute__((ext_vector_type(8))) __bf16 bf16x8;
typedef __attribute__((ext_vector_type(4))) float f32x4;
typedef _Float16 f16;
typedef __attribute__((ext_vector_type(2))) _Float16 f16x2;

namespace {
constexpr int GP = 512;
}

__device__ inline unsigned short f2bf(float x) {
  union { float f; unsigned u; } v; v.f = x;
  unsigned r = v.u + 0x7fff + ((v.u >> 16) & 1);   // RNE
  return (unsigned short)(r >> 16);
}

__device__ inline void cvt8_store(unsigned short* dst, float4 a, float4 b) {
  ushort4 lo, hi;
  lo.x = f2bf(a.x); lo.y = f2bf(a.y); lo.z = f2bf(a.z); lo.w = f2bf(a.w);
  hi.x = f2bf(b.x); hi.y = f2bf(b.y); hi.z = f2bf(b.z); hi.w = f2bf(b.w);
  *(ushort4*)dst = lo; *(ushort4*)(dst + 4) = hi;
}

// ---------------------------------------------------------------------------
// Kernel 1: QKV projection (bf16 MFMA, fp32->bf16 in staging) +
// log1p(relu)-lam + fp16-packed tropical linear + scramble-write (fp16).
// grid (24,16).
// ---------------------------------------------------------------------------
__global__ __launch_bounds__(256) void k_gemm0t(const float* __restrict__ h,
    const float* __restrict__ Wq, const float* __restrict__ Wkv,
    const float* __restrict__ lam, const float* __restrict__ Wqt,
    const float* __restrict__ Wkt, const float* __restrict__ Wvt,
    f16* __restrict__ qkvh)
{
  __shared__ unsigned short As[64][72];
  __shared__ unsigned short Bs[64][72];
  __shared__ float Wl[64][65];
  __shared__ f16 nl[64][72];
  const int tid = threadIdx.x;
  const int bx = blockIdx.x;
  const int r0 = blockIdx.y * 64, c0 = bx * 64;
  const int which = c0 >> 9;            // 0=q,1=k,2=v
  const int hh = bx & 7;                // head
  const float* Wt = (which == 0) ? Wqt : (which == 1) ? Wkt : Wvt;
  #pragma unroll
  for (int q = 0; q < 16; ++q) {
    int idx = q * 256 + tid;
    Wl[idx >> 6][idx & 63] = Wt[idx];
  }
  const int w = tid >> 6, l = tid & 63;
  const int wr = (w >> 1) * 32, wc = (w & 1) * 32;
  const int srow = tid >> 3, sk8 = (tid & 7) * 8;
  f32x4 acc[2][2] = {};
  for (int kk = 0; kk < 512; kk += 64) {
    __syncthreads();
    #pragma unroll
    for (int q2 = 0; q2 < 2; ++q2) {
      int row = srow + q2 * 32;
      const float* ap = &h[(r0 + row) * 512 + kk + sk8];
      cvt8_store(&As[row][sk8], *(const float4*)ap, *(const float4*)(ap + 4));
      int c = c0 + row;
      const float* wrp = (c < 512) ? (Wq + c * 512) : (Wkv + (c - 512) * 512);
      cvt8_store(&Bs[row][sk8], *(const float4*)&wrp[kk + sk8],
                 *(const float4*)&wrp[kk + sk8 + 4]);
    }
    __syncthreads();
    #pragma unroll
    for (int ks = 0; ks < 2; ++ks) {
      const int kc = ks * 32 + (l >> 4) * 8;
      bf16x8 a0 = *(const bf16x8*)&As[wr +      (l & 15)][kc];
      bf16x8 a1 = *(const bf16x8*)&As[wr + 16 + (l & 15)][kc];
      bf16x8 b0 = *(const bf16x8*)&Bs[wc +      (l & 15)][kc];
      bf16x8 b1 = *(const bf16x8*)&Bs[wc + 16 + (l & 15)][kc];
      acc[0][0] = __builtin_amdgcn_mfma_f32_16x16x32_bf16(a0, b0, acc[0][0], 0, 0, 0);
      acc[0][1] = __builtin_amdgcn_mfma_f32_16x16x32_bf16(a0, b1, acc[0][1], 0, 0, 0);
      acc[1][0] = __builtin_amdgcn_mfma_f32_16x16x32_bf16(a1, b0, acc[1][0], 0, 0, 0);
      acc[1][1] = __builtin_amdgcn_mfma_f32_16x16x32_bf16(a1, b1, acc[1][1], 0, 0, 0);
    }
  }
  #pragma unroll
  for (int i = 0; i < 2; ++i)
    #pragma unroll
    for (int j = 0; j < 2; ++j)
      #pragma unroll
      for (int r = 0; r < 4; ++r) {
        int rl = wr + i * 16 + (l >> 4) * 4 + r;
        int cl = wc + j * 16 + (l & 15);
        nl[rl][cl] = (f16)(log1pf(fmaxf(acc[i][j][r], 0.f)) - lam[hh * 64 + cl]);
      }
  __syncthreads();
  // per-lane tropical weight row, packed fp16 (32 VGPRs)
  f16x2 wreg[32];
  #pragma unroll
  for (int i = 0; i < 64; i += 2)
    wreg[i / 2] = f16x2{ (f16)Wl[l][i], (f16)Wl[l][i + 1] };
  const f16 NEGI = (f16)(-INFINITY);
  #pragma unroll 2
  for (int it = 0; it < 16; ++it) {
    int lr = w + it * 4;                 // wave-uniform row -> broadcast reads
    f16x2 m2 = f16x2{ NEGI, NEGI };
    #pragma unroll
    for (int i = 0; i < 8; ++i) {
      f16x2 nv[4];
      *(int4*)&nv[0] = *(const int4*)&nl[lr][i * 8];
      m2 = __builtin_elementwise_max(m2, nv[0] + wreg[i * 4 + 0]);
      m2 = __builtin_elementwise_max(m2, nv[1] + wreg[i * 4 + 1]);
      m2 = __builtin_elementwise_max(m2, nv[2] + wreg[i * 4 + 2]);
      m2 = __builtin_elementwise_max(m2, nv[3] + wreg[i * 4 + 3]);
    }
    f16 m = (m2[0] > m2[1]) ? m2[0] : m2[1];
    int r = r0 + lr;
    int s = r >> 1, bb = r & 1;
    int g = bb * 8 + (s >> 6);
    int p = ((s & 63) << 3) | hh;
    qkvh[which * 524288 + ((g << 9) + p) * 64 + l] = m;
  }
}

// ---------------------------------------------------------------------------
// Kernel 2: tropical attention, packed fp16.  Block = 64 p-rows x 64 c-cols.
// grid (8 pt, 16 g, 8 cs).  fp16 partial ctx out (8 c-splits).
// ---------------------------------------------------------------------------
__global__ __launch_bounds__(256) void k_attn(const f16* __restrict__ qkv,
    f16* __restrict__ ctxp)
{
  const int pt = blockIdx.x;        // 0..7
  const int g  = blockIdx.y;        // 0..15
  const int cs = blockIdx.z;        // 0..7
  const f16* qb = qkv +           (size_t)g * GP * 64;
  const f16* kb = qkv + 524288  + (size_t)g * GP * 64;
  const f16* vb = qkv + 1048576 + (size_t)g * GP * 64;
  __shared__ f16 qs[64][64];
  __shared__ f16 ks[64][64];
  __shared__ f16 vs[64][64];
  __shared__ f16 ss[64][68];        // transposed: [c][p]
  const int tid = threadIdx.x;
  const int tr = tid >> 4, tc = tid & 15;
  {
    int row = tid >> 3, blk = tid & 7;
    int c0 = cs * 64;
    #pragma unroll
    for (int q2 = 0; q2 < 2; ++q2) {
      int r = row + q2 * 32;
      int sb = (blk ^ (r & 7)) * 8;
      *(int4*)&qs[r][sb] = *(const int4*)&qb[(pt * 64 + r) * 64 + blk * 8];
      *(int4*)&ks[r][sb] = *(const int4*)&kb[(c0 + r) * 64 + blk * 8];
      *(int4*)&vs[r][sb] = *(const int4*)&vb[(c0 + r) * 64 + blk * 8];
    }
  }
  __syncthreads();
  const f16 NEGI = (f16)(-INFINITY);
  const f16 POSI = (f16)(INFINITY);
  const f16x2 NEG2 = { NEGI, NEGI };
  const f16x2 POS2 = { POSI, POSI };
  // ---- phase 1: 16 scores (rows 4tr+i, cols tc+16m), d packed 2/op ----
  f16x2 mx2[4][4], mn2[4][4];
  #pragma unroll
  for (int i = 0; i < 4; ++i)
    #pragma unroll
    for (int m = 0; m < 4; ++m) { mx2[i][m] = NEG2; mn2[i][m] = POS2; }
  #pragma unroll
  for (int b = 0; b < 8; ++b) {
    f16x2 qv[4][4], kv[4][4];
    #pragma unroll
    for (int i = 0; i < 4; ++i) {
      int r = 4 * tr + i;
      *(int4*)&qv[i][0] = *(const int4*)&qs[r][(b ^ (r & 7)) * 8];
    }
    #pragma unroll
    for (int m = 0; m < 4; ++m)
      *(int4*)&kv[m][0] = *(const int4*)&ks[tc + 16 * m][(b ^ (tc & 7)) * 8];
    #pragma unroll
    for (int i = 0; i < 4; ++i)
      #pragma unroll
      for (int m = 0; m < 4; ++m)
        #pragma unroll
        for (int e = 0; e < 4; ++e) {
          f16x2 d = qv[i][e] - kv[m][e];
          mx2[i][m] = __builtin_elementwise_max(mx2[i][m], d);
          mn2[i][m] = __builtin_elementwise_min(mn2[i][m], d);
        }
  }
  #pragma unroll
  for (int i = 0; i < 4; ++i)
    #pragma unroll
    for (int m = 0; m < 4; ++m) {
      f16 mxv = (mx2[i][m][0] > mx2[i][m][1]) ? mx2[i][m][0] : mx2[i][m][1];
      f16 mnv = (mn2[i][m][0] < mn2[i][m][1]) ? mn2[i][m][0] : mn2[i][m][1];
      ss[tc + 16 * m][4 * tr + i] = mnv - mxv;
    }
  __syncthreads();
  // ---- phase 2: ctx over c-half (tc>>3), dims group dg = tc&7 ----
  f16x2 ctx[4][4];
  #pragma unroll
  for (int i = 0; i < 4; ++i)
    #pragma unroll
    for (int j = 0; j < 4; ++j) ctx[i][j] = NEG2;
  const int ch = tc >> 3, dg = tc & 7;
  #pragma unroll
  for (int gi = 0; gi < 4; ++gi) {
    #pragma unroll
    for (int e = 0; e < 8; ++e) {
      int c = ch * 32 + gi * 8 + e;
      f16x2 vv[4];
      *(int4*)&vv[0] = *(const int4*)&vs[c][(dg ^ (c & 7)) * 8];
      f16 sr[4];
      *(int2*)&sr[0] = *(const int2*)&ss[c][4 * tr];
      #pragma unroll
      for (int i = 0; i < 4; ++i) {
        f16x2 s2 = { sr[i], sr[i] };
        #pragma unroll
        for (int j = 0; j < 4; ++j)
          ctx[i][j] = __builtin_elementwise_max(ctx[i][j], s2 + vv[j]);
      }
    }
  }
  #pragma unroll
  for (int i = 0; i < 4; ++i)
    #pragma unroll
    for (int j = 0; j < 4; ++j) {
      int o = __shfl_xor(*(int*)&ctx[i][j], 8);
      ctx[i][j] = __builtin_elementwise_max(ctx[i][j], *(f16x2*)&o);
    }
  if (tc < 8) {
    size_t base = (size_t)cs * 524288 + (size_t)g * 32768
                + (size_t)(pt * 64 + 4 * tr) * 64 + dg * 8;
    #pragma unroll
    for (int i = 0; i < 4; ++i) {
      int4 o;
      ((f16x2*)&o)[0] = ctx[i][0];
      ((f16x2*)&o)[1] = ctx[i][1];
      ((f16x2*)&o)[2] = ctx[i][2];
      ((f16x2*)&o)[3] = ctx[i][3];
      *(int4*)&ctxp[base + i * 64] = o;
    }
  }
}

// ---------------------------------------------------------------------------
// Kernel 3: combine 8 fp16 c-split partials ONCE: max, expm1, bf16,
// unscramble-write to avb [S*B][512].
// ---------------------------------------------------------------------------
__global__ __launch_bounds__(256) void k_comb(const f16* __restrict__ ctxp,
    unsigned short* __restrict__ avb)
{
  int idx = blockIdx.x * 256 + threadIdx.x;   // 65536 int4s (8 fp16 each)
  int dblk = idx & 7, p = (idx >> 3) & 511, g = idx >> 12;
  const f16* cp = ctxp + (size_t)g * 32768 + p * 64 + dblk * 8;
  f16x2 m[4];
  *(int4*)&m[0] = *(const int4*)cp;
  #pragma unroll
  for (int cs = 1; cs < 8; ++cs) {
    f16x2 t[4];
    *(int4*)&t[0] = *(const int4*)(cp + (size_t)cs * 524288);
    #pragma unroll
    for (int e = 0; e < 4; ++e) m[e] = __builtin_elementwise_max(m[e], t[e]);
  }
  ushort4 lo, hi;
  lo.x = f2bf(expm1f((float)m[0][0]));
  lo.y = f2bf(expm1f((float)m[0][1]));
  lo.z = f2bf(expm1f((float)m[1][0]));
  lo.w = f2bf(expm1f((float)m[1][1]));
  hi.x = f2bf(expm1f((float)m[2][0]));
  hi.y = f2bf(expm1f((float)m[2][1]));
  hi.z = f2bf(expm1f((float)m[3][0]));
  hi.w = f2bf(expm1f((float)m[3][1]));
  unsigned short* dst = avb + (p * 2 + (g >> 3)) * 512 + (g & 7) * 64 + dblk * 8;
  *(ushort4*)dst = lo;
  *(ushort4*)(dst + 4) = hi;
}

// ---------------------------------------------------------------------------
// Kernel 4: output GEMM; A from compact bf16 avb (L2-resident), B = Wo
// converted fp32->bf16 in staging.
// ---------------------------------------------------------------------------
__global__ __launch_bounds__(256) void k_gemm1c(const unsigned short* __restrict__ avb,
    const float* __restrict__ Wo, float* __restrict__ ao)
{
  __shared__ unsigned short As[64][72];
  __shared__ unsigned short Bs[64][72];
  const int tid = threadIdx.x;
  const int r0 = blockIdx.y * 64, c0 = blockIdx.x * 64;
  const int w = tid >> 6, l = tid & 63;
  const int wr = (w >> 1) * 32, wc = (w & 1) * 32;
  const int srow = tid >> 3, sk8 = (tid & 7) * 8;
  f32x4 acc[2][2] = {};
  for (int kk = 0; kk < 512; kk += 64) {
    __syncthreads();
    #pragma unroll
    for (int q2 = 0; q2 < 2; ++q2) {
      int row = srow + q2 * 32;
      *(int4*)&As[row][sk8] = *(const int4*)&avb[(r0 + row) * 512 + kk + sk8];
      const float* bp = &Wo[(c0 + row) * 512 + kk + sk8];
      cvt8_store(&Bs[row][sk8], *(const float4*)bp, *(const float4*)(bp + 4));
    }
    __syncthreads();
    #pragma unroll
    for (int ks = 0; ks < 2; ++ks) {
      const int kc = ks * 32 + (l >> 4) * 8;
      bf16x8 a0 = *(const bf16x8*)&As[wr +      (l & 15)][kc];
      bf16x8 a1 = *(const bf16x8*)&As[wr + 16 + (l & 15)][kc];
      bf16x8 b0 = *(const bf16x8*)&Bs[wc +      (l & 15)][kc];
      bf16x8 b1 = *(const bf16x8*)&Bs[wc + 16 + (l & 15)][kc];
      acc[0][0] = __builtin_amdgcn_mfma_f32_16x16x32_bf16(a0, b0, acc[0][0], 0, 0, 0);
      acc[0][1] = __builtin_amdgcn_mfma_f32_16x16x32_bf16(a0, b1, acc[0][1], 0, 0, 0);
      acc[1][0] = __builtin_amdgcn_mfma_f32_16x16x32_bf16(a1, b0, acc[1][0], 0, 0, 0);
      acc[1][1] = __builtin_amdgcn_mfma_f32_16x16x32_bf16(a1, b1, acc[1][1], 0, 0, 0);
    }
  }
  #pragma unroll
  for (int i = 0; i < 2; ++i)
    #pragma unroll
    for (int j = 0; j < 2; ++j)
      #pragma unroll
      for (int r = 0; r < 4; ++r) {
        int row = r0 + wr + i * 16 + (l >> 4) * 4 + r;
        int col = c0 + wc + j * 16 + (l & 15);
        ao[row * 512 + col] = acc[i][j][r];
      }
}

// ---------------------------------------------------------------------------
// Kernel 5: residual + LayerNorm, one WAVE per row
// ---------------------------------------------------------------------------
__global__ __launch_bounds__(256) void k_ln(const float* __restrict__ hin,
    const float* __restrict__ ao, const float* __restrict__ gamma,
    const float* __restrict__ beta, float* __restrict__ outp)
{
  const int r = blockIdx.x * 4 + (threadIdx.x >> 6);
  const int lane = threadIdx.x & 63;
  const int c0 = lane * 8;
  f32x4 h0 = *(const f32x4*)&hin[r * 512 + c0];
  f32x4 h1 = *(const f32x4*)&hin[r * 512 + c0 + 4];
  f32x4 a0 = *(const f32x4*)&ao[r * 512 + c0];
  f32x4 a1 = *(const f32x4*)&ao[r * 512 + c0 + 4];
  float x[8];
  #pragma unroll
  for (int e = 0; e < 4; ++e) { x[e] = h0[e] + a0[e]; x[4 + e] = h1[e] + a1[e]; }
  float sum = 0.f, sq = 0.f;
  #pragma unroll
  for (int e = 0; e < 8; ++e) { sum += x[e]; sq += x[e] * x[e]; }
  #pragma unroll
  for (int o = 32; o > 0; o >>= 1) {
    sum += __shfl_xor(sum, o);
    sq  += __shfl_xor(sq, o);
  }
  float mu  = sum * (1.f / 512.f);
  float var = sq * (1.f / 512.f) - mu * mu;
  float rstd = rsqrtf(fmaxf(var, 0.f) + 1e-5f);
  f32x4 o0, o1;
  #pragma unroll
  for (int e = 0; e < 4; ++e) {
    o0[e] = (x[e]     - mu) * rstd * gamma[c0 + e]     + beta[c0 + e];
    o1[e] = (x[4 + e] - mu) * rstd * gamma[c0 + 4 + e] + beta[c0 + 4 + e];
  }
  *(f32x4*)&outp[r * 512 + c0]     = o0;
  *(f32x4*)&outp[r * 512 + c0 + 4] = o1;
}

// ---------------------------------------------------------------------------
extern "C" void kernel_launch(void* const* d_in, const int* in_sizes, int n_in,
                              void* d_out, int out_size, void* d_ws, size_t ws_size,
                              hipStream_t stream) {
  const float* hin   = (const float*)d_in[0];
  const float* Wq    = (const float*)d_in[1];
  const float* Wkv   = (const float*)d_in[2];
  const float* Wqt   = (const float*)d_in[3];
  const float* Wkt   = (const float*)d_in[4];
  const float* Wvt   = (const float*)d_in[5];
  const float* lam   = (const float*)d_in[6];
  const float* Wo    = (const float*)d_in[7];
  const float* gamma = (const float*)d_in[8];
  const float* beta  = (const float*)d_in[9];
  char* wsb = (char*)d_ws;
  // byte layout: [0,3M)  qkvh fp16 (dead after attn; ao fp32 overlays [0,2M))
  //              [4M,5M) avb bf16 | [6M,14M) ctxp fp16 (8 c-splits x 1MB)
  f16*            qkvh = (f16*)wsb;
  f16*            ctxp = (f16*)(wsb + 6291456);
  unsigned short* avb  = (unsigned short*)(wsb + 4194304);
  float*          ao   = (float*)wsb;
  float*          out  = (float*)d_out;

  k_gemm0t<<<dim3(24, 16),   256, 0, stream>>>(hin, Wq, Wkv, lam, Wqt, Wkt, Wvt, qkvh);
  k_attn  <<<dim3(8, 16, 8), 256, 0, stream>>>(qkvh, ctxp);
  k_comb  <<<dim3(256),      256, 0, stream>>>(ctxp, avb);
  k_gemm1c<<<dim3(8, 16),    256, 0, stream>>>(avb, Wo, ao);
  k_ln    <<<dim3(256),      256, 0, stream>>>(hin, ao, gamma, beta, out);
}